// Round 15
// baseline (136.384 us; speedup 1.0000x reference)
//
#include <hip/hip_runtime.h>
#include <hip/hip_bf16.h>
#include <hip/hip_fp16.h>
#include <math.h>

#define NN 50000
#define EE 800000
#define FIN 256
#define FH 96
#define FC 40
#define NBK 196   // ceil(50000/256) buckets of 256 nodes

typedef _Float16 h4 __attribute__((ext_vector_type(4)));
typedef _Float16 h8 __attribute__((ext_vector_type(8)));
typedef float f32x4 __attribute__((ext_vector_type(4)));

// pack: low16 = row (N<65536), high16 = fp16 bits of w (= dinv[row]*ew)
__device__ __forceinline__ unsigned pack_edge(int row, float w) {
    _Float16 he = (_Float16)w;
    unsigned short us;
    __builtin_memcpy(&us, &he, 2);
    return (unsigned)row | ((unsigned)us << 16);
}
__device__ __forceinline__ float unpack_w(unsigned pk) {
    unsigned short us = (unsigned short)(pk >> 16);
    _Float16 hv;
    __builtin_memcpy(&hv, &us, 2);
    return (float)hv;
}

// ---------------- fused launch 1 ----------------
// blocks [0,782): GEMM1 (MFMA fp16, raw x@W1^T), register-prefetch pipelined
// blocks [782,910): row-degree histogram, 4 quarters x 32 slices, 25KB LDS
// blocks [910,974): col bucket-count -> private bcnt2d rows

#define G1B 782

__global__ __launch_bounds__(256) void k_fused1(const float* __restrict__ x,
                                                const float* __restrict__ W,
                                                _Float16* __restrict__ g0h,
                                                const int* __restrict__ ei, int E,
                                                unsigned* __restrict__ copies,
                                                unsigned* __restrict__ bcnt2d, int n) {
    __shared__ unsigned lds[6250];   // 25000 B; gemm branch uses 23040 B of it
    int bid = blockIdx.x;
    int tid = threadIdx.x;

    if (bid < G1B) {
        // ---- GEMM1, prefetch-pipelined ----
        _Float16* xsp = (_Float16*)lds;          // [64][72]
        _Float16* wsp = xsp + 64 * 72;           // [96][72]
        int row0 = bid * 64;
        int l = tid & 63, w = tid >> 6;
        int l15 = l & 15, lg = l >> 4;

        f32x4 acc[6];
#pragma unroll
        for (int c = 0; c < 6; ++c) acc[c] = (f32x4)0.f;

        float4 px[4], pw[6];
        // load chunk 0
        {
#pragma unroll
            for (int i = 0; i < 4; ++i) {
                int it = tid + 256 * i;
                int r = it >> 4, k4 = it & 15;
                int gr = row0 + r;
                px[i] = make_float4(0.f, 0.f, 0.f, 0.f);
                if (gr < n) px[i] = *(const float4*)&x[gr * FIN + k4 * 4];
            }
#pragma unroll
            for (int i = 0; i < 6; ++i) {
                int it = tid + 256 * i;
                int r = it >> 4, k4 = it & 15;
                pw[i] = *(const float4*)&W[r * FIN + k4 * 4];
            }
        }
        for (int kc = 0; kc < 4; ++kc) {
            // store current chunk to LDS
#pragma unroll
            for (int i = 0; i < 4; ++i) {
                int it = tid + 256 * i;
                int r = it >> 4, k4 = it & 15;
                h4 hv = {(_Float16)px[i].x, (_Float16)px[i].y, (_Float16)px[i].z, (_Float16)px[i].w};
                *(h4*)&xsp[r * 72 + k4 * 4] = hv;
            }
#pragma unroll
            for (int i = 0; i < 6; ++i) {
                int it = tid + 256 * i;
                int r = it >> 4, k4 = it & 15;
                h4 hv = {(_Float16)pw[i].x, (_Float16)pw[i].y, (_Float16)pw[i].z, (_Float16)pw[i].w};
                *(h4*)&wsp[r * 72 + k4 * 4] = hv;
            }
            // issue next chunk's loads (latency hides under MFMA + syncs)
            if (kc < 3) {
                int kbase = (kc + 1) * 64;
#pragma unroll
                for (int i = 0; i < 4; ++i) {
                    int it = tid + 256 * i;
                    int r = it >> 4, k4 = it & 15;
                    int gr = row0 + r;
                    px[i] = make_float4(0.f, 0.f, 0.f, 0.f);
                    if (gr < n) px[i] = *(const float4*)&x[gr * FIN + kbase + k4 * 4];
                }
#pragma unroll
                for (int i = 0; i < 6; ++i) {
                    int it = tid + 256 * i;
                    int r = it >> 4, k4 = it & 15;
                    pw[i] = *(const float4*)&W[r * FIN + kbase + k4 * 4];
                }
            }
            __syncthreads();
#pragma unroll
            for (int ks = 0; ks < 2; ++ks) {
                h8 a = *(const h8*)&xsp[(16 * w + l15) * 72 + ks * 32 + lg * 8];
#pragma unroll
                for (int ct = 0; ct < 6; ++ct) {
                    h8 b = *(const h8*)&wsp[(ct * 16 + l15) * 72 + ks * 32 + lg * 8];
                    acc[ct] = __builtin_amdgcn_mfma_f32_16x16x32_f16(a, b, acc[ct], 0, 0, 0);
                }
            }
            __syncthreads();
        }
#pragma unroll
        for (int r = 0; r < 4; ++r) {
            int grow = row0 + 16 * w + lg * 4 + r;
            if (grow < n) {
#pragma unroll
                for (int ct = 0; ct < 6; ++ct)
                    g0h[(size_t)grow * FH + ct * 16 + l15] = (_Float16)acc[ct][r];
            }
        }
    } else if (bid < 910) {
        // ---- row-degree histogram: quarter q, slice of E/32 ----
        int b2 = bid - G1B;           // 0..127
        int q = b2 >> 5;              // node quarter 0..3
        int slice = b2 & 31;
        int ES2 = (E + 31) >> 5;      // 25000
        const int* ptr = ei;          // row
        for (int i = tid; i < 6250; i += 256) lds[i] = 0u;
        __syncthreads();
        int lo = slice * ES2, hi = min(lo + ES2, E);
        int nlo = q * 12500;
        for (int i = lo + tid; i < hi; i += 256) {
            int rel = ptr[i] - nlo;
            if ((unsigned)rel < 12500u)
                atomicAdd(&lds[rel >> 1], 1u << ((rel & 1) << 4));
        }
        __syncthreads();
        unsigned* dst = copies + (size_t)b2 * 6250;
        for (int i = tid; i < 6250; i += 256) dst[i] = lds[i];
    } else {
        // ---- col bucket-count (private row per chunk) ----
        int chunk = bid - 910;
        int ES = (E + 63) >> 6;
        const int* col = ei + E;
        for (int i = tid; i < NBK; i += 256) lds[i] = 0u;
        __syncthreads();
        int lo = chunk * ES, hi = min(lo + ES, E);
        for (int i = lo + tid; i < hi; i += 256) atomicAdd(&lds[col[i] >> 8], 1u);
        __syncthreads();
        for (int i = tid; i < NBK; i += 256) bcnt2d[chunk * 256 + i] = lds[i];
    }
}

// ---------------- reduce row-copies -> dinv; block 0 sums bcnt2d + scans -> bstart/gcur ----------------

__global__ __launch_bounds__(256) void k_reduce(const unsigned* __restrict__ copies,
                                                const unsigned* __restrict__ bcnt2d,
                                                float* __restrict__ dinv,
                                                unsigned* __restrict__ bstart,
                                                unsigned* __restrict__ gcur,
                                                unsigned* __restrict__ off, unsigned E) {
    int t = blockIdx.x * blockDim.x + threadIdx.x;  // 0..25087
    if (t < 25000) {
        int quarter = t / 6250, w = t - quarter * 6250;
        unsigned sr = 0;
        const unsigned* br = copies + (size_t)(quarter * 32) * 6250 + w;
#pragma unroll 8
        for (int s = 0; s < 32; ++s) sr += br[s * 6250];
        int n0 = quarter * 12500 + 2 * w;
        dinv[n0]     = rsqrtf((float)((sr & 0xffffu) + 1u));
        dinv[n0 + 1] = rsqrtf((float)((sr >> 16) + 1u));
    }
    if (blockIdx.x == 0) {
        __shared__ unsigned sb[256];
        int tt = threadIdx.x;
        unsigned v = 0;
        if (tt < NBK) {
#pragma unroll 8
            for (int c = 0; c < 64; ++c) v += bcnt2d[c * 256 + tt];
        }
        sb[tt] = v;
        __syncthreads();
        for (int o = 1; o < 256; o <<= 1) {
            unsigned tv = (tt >= o) ? sb[tt - o] : 0u;
            __syncthreads();
            sb[tt] += tv;
            __syncthreads();
        }
        if (tt < NBK) {
            unsigned ex = sb[tt] - v;     // exclusive
            bstart[tt] = ex;
            gcur[tt] = ex;
            bstart[tt + 1] = sb[tt];
        }
        if (tt == 0) off[NN] = E;
    }
}

// ---------------- P1: coarse bucket by col>>8; payload packs dinv[row]*ew ----------------

__global__ __launch_bounds__(256) void k_bucket(const int* __restrict__ row,
                                                const int* __restrict__ col,
                                                const float* __restrict__ ew,
                                                const float* __restrict__ dinv,
                                                unsigned* __restrict__ gcur,
                                                unsigned* __restrict__ bkc,
                                                unsigned* __restrict__ bkpk, int E) {
    __shared__ unsigned cnt[NBK];
    __shared__ unsigned cur[NBK];
    int tid = threadIdx.x;
    int CH = (E + gridDim.x - 1) / gridDim.x;
    int lo = blockIdx.x * CH, hi = min(lo + CH, E);
    for (int i = tid; i < NBK; i += 256) cnt[i] = 0u;
    __syncthreads();
    for (int i = lo + tid; i < hi; i += 256) atomicAdd(&cnt[col[i] >> 8], 1u);
    __syncthreads();
    for (int i = tid; i < NBK; i += 256) cur[i] = atomicAdd(&gcur[i], cnt[i]);
    __syncthreads();
    for (int i = lo + tid; i < hi; i += 256) {
        int c = col[i];
        int r = row[i];
        unsigned pos = atomicAdd(&cur[c >> 8], 1u);
        bkc[pos] = (unsigned)c;
        bkpk[pos] = pack_edge(r, dinv[r] * ew[i]);
    }
}

// ---------------- P2: per-bucket count + scan -> off[], then exact place ----------------

__global__ __launch_bounds__(256) void k_place(const unsigned* __restrict__ bkc,
                                               const unsigned* __restrict__ bkpk,
                                               const unsigned* __restrict__ bstart,
                                               unsigned* __restrict__ off,
                                               unsigned* __restrict__ epk, int n) {
    __shared__ unsigned cnt[256];
    __shared__ unsigned cur[256];
    int b = blockIdx.x;
    int tid = threadIdx.x;
    int node0 = b * 256;
    unsigned st = bstart[b], en = bstart[b + 1];
    cnt[tid] = 0u;
    __syncthreads();
    for (unsigned i = st + tid; i < en; i += 256) atomicAdd(&cnt[bkc[i] & 255], 1u);
    __syncthreads();
    unsigned v = cnt[tid];
    cur[tid] = v;
    __syncthreads();
    for (int o = 1; o < 256; o <<= 1) {
        unsigned tv = (tid >= o) ? cur[tid - o] : 0u;
        __syncthreads();
        cur[tid] += tv;
        __syncthreads();
    }
    unsigned base = st + cur[tid] - v;
    int node = node0 + tid;
    if (node < n) off[node] = base;
    cur[tid] = base;
    __syncthreads();
    for (unsigned i = st + tid; i < en; i += 256) {
        unsigned c = bkc[i];
        unsigned pos = atomicAdd(&cur[c & 255], 1u);
        epk[pos] = bkpk[i];
    }
}

// ---------------- aggregation 96: 12 threads/node, h8 gathers, unroll-8/4 ----------------

__global__ __launch_bounds__(256) void k_agg96(const _Float16* __restrict__ g0h,
                                               const unsigned* __restrict__ off,
                                               const unsigned* __restrict__ epk,
                                               const float* __restrict__ dinv,
                                               const float* __restrict__ b,
                                               _Float16* __restrict__ outh, int n) {
    int tid = blockIdx.x * 256 + threadIdx.x;
    int node = tid / 12;
    int f8 = tid - node * 12;
    if (node >= n) return;
    float s = dinv[node];
    const h8* gp = (const h8*)g0h;  // row = 12 h8 chunks
    h8 self = gp[(size_t)node * 12 + f8];
    float acc[8];
#pragma unroll
    for (int j = 0; j < 8; ++j) acc[j] = s * (float)self[j];
    unsigned st = off[node], en = off[node + 1];
    unsigned e = st;
    for (; e + 8 <= en; e += 8) {
        unsigned k0 = epk[e + 0], k1 = epk[e + 1], k2 = epk[e + 2], k3 = epk[e + 3];
        unsigned k4 = epk[e + 4], k5 = epk[e + 5], k6 = epk[e + 6], k7 = epk[e + 7];
        h8 ga = gp[(size_t)(k0 & 0xffffu) * 12 + f8];
        h8 gb = gp[(size_t)(k1 & 0xffffu) * 12 + f8];
        h8 gc = gp[(size_t)(k2 & 0xffffu) * 12 + f8];
        h8 gd = gp[(size_t)(k3 & 0xffffu) * 12 + f8];
        h8 ge = gp[(size_t)(k4 & 0xffffu) * 12 + f8];
        h8 gf = gp[(size_t)(k5 & 0xffffu) * 12 + f8];
        h8 gg = gp[(size_t)(k6 & 0xffffu) * 12 + f8];
        h8 gh = gp[(size_t)(k7 & 0xffffu) * 12 + f8];
        float w0 = unpack_w(k0), w1 = unpack_w(k1), w2 = unpack_w(k2), w3 = unpack_w(k3);
        float w4 = unpack_w(k4), w5 = unpack_w(k5), w6 = unpack_w(k6), w7 = unpack_w(k7);
#pragma unroll
        for (int j = 0; j < 8; ++j) acc[j] = fmaf(w0, (float)ga[j], acc[j]);
#pragma unroll
        for (int j = 0; j < 8; ++j) acc[j] = fmaf(w1, (float)gb[j], acc[j]);
#pragma unroll
        for (int j = 0; j < 8; ++j) acc[j] = fmaf(w2, (float)gc[j], acc[j]);
#pragma unroll
        for (int j = 0; j < 8; ++j) acc[j] = fmaf(w3, (float)gd[j], acc[j]);
#pragma unroll
        for (int j = 0; j < 8; ++j) acc[j] = fmaf(w4, (float)ge[j], acc[j]);
#pragma unroll
        for (int j = 0; j < 8; ++j) acc[j] = fmaf(w5, (float)gf[j], acc[j]);
#pragma unroll
        for (int j = 0; j < 8; ++j) acc[j] = fmaf(w6, (float)gg[j], acc[j]);
#pragma unroll
        for (int j = 0; j < 8; ++j) acc[j] = fmaf(w7, (float)gh[j], acc[j]);
    }
    for (; e + 4 <= en; e += 4) {
        unsigned k0 = epk[e + 0], k1 = epk[e + 1], k2 = epk[e + 2], k3 = epk[e + 3];
        h8 ga = gp[(size_t)(k0 & 0xffffu) * 12 + f8];
        h8 gb = gp[(size_t)(k1 & 0xffffu) * 12 + f8];
        h8 gc = gp[(size_t)(k2 & 0xffffu) * 12 + f8];
        h8 gd = gp[(size_t)(k3 & 0xffffu) * 12 + f8];
        float w0 = unpack_w(k0), w1 = unpack_w(k1), w2 = unpack_w(k2), w3 = unpack_w(k3);
#pragma unroll
        for (int j = 0; j < 8; ++j) acc[j] = fmaf(w0, (float)ga[j], acc[j]);
#pragma unroll
        for (int j = 0; j < 8; ++j) acc[j] = fmaf(w1, (float)gb[j], acc[j]);
#pragma unroll
        for (int j = 0; j < 8; ++j) acc[j] = fmaf(w2, (float)gc[j], acc[j]);
#pragma unroll
        for (int j = 0; j < 8; ++j) acc[j] = fmaf(w3, (float)gd[j], acc[j]);
    }
    for (; e < en; ++e) {
        unsigned k = epk[e];
        h8 g = gp[(size_t)(k & 0xffffu) * 12 + f8];
        float wv = unpack_w(k);
#pragma unroll
        for (int j = 0; j < 8; ++j) acc[j] = fmaf(wv, (float)g[j], acc[j]);
    }
    float4 bv0 = ((const float4*)b)[f8 * 2];
    float4 bv1 = ((const float4*)b)[f8 * 2 + 1];
    const float bb[8] = {bv0.x, bv0.y, bv0.z, bv0.w, bv1.x, bv1.y, bv1.z, bv1.w};
    h8 o;
#pragma unroll
    for (int j = 0; j < 8; ++j) o[j] = (_Float16)fmaxf(fmaf(s, acc[j], bb[j]), 0.f);
    *(h8*)&outh[(size_t)node * FH + f8 * 8] = o;
}

// ---------------- GEMM2 (MFMA fp16): g1h = fp16( h @ W2^T ) raw ----------------

__global__ __launch_bounds__(256) void k_gemm2(const _Float16* __restrict__ h,
                                               const float* __restrict__ W2,
                                               _Float16* __restrict__ g1h, int n) {
    __shared__ _Float16 hs[64][104];
    __shared__ _Float16 wsm[48][104];
    int tid = threadIdx.x;
    int row0 = blockIdx.x * 64;
    int l = tid & 63, w = tid >> 6;
    int l15 = l & 15, lg = l >> 4;

    f32x4 acc[3];
#pragma unroll
    for (int c = 0; c < 3; ++c) acc[c] = (f32x4)0.f;

#pragma unroll
    for (int i = 0; i < 6; ++i) {
        int it = tid + 256 * i;
        int r = it / 24, k4 = it - r * 24;
        int gr = row0 + r;
        h4 hv = {(_Float16)0.f, (_Float16)0.f, (_Float16)0.f, (_Float16)0.f};
        if (gr < n) hv = *(const h4*)&h[(size_t)gr * FH + k4 * 4];
        *(h4*)&hs[r][k4 * 4] = hv;
    }
#pragma unroll
    for (int i = 0; i < 5; ++i) {
        int it = tid + 256 * i;
        if (it < 1152) {
            int r = it / 24, k4 = it - r * 24;
            h4 hv = {(_Float16)0.f, (_Float16)0.f, (_Float16)0.f, (_Float16)0.f};
            if (r < FC) {
                float4 v = *(const float4*)&W2[r * FH + k4 * 4];
                hv[0] = (_Float16)v.x; hv[1] = (_Float16)v.y;
                hv[2] = (_Float16)v.z; hv[3] = (_Float16)v.w;
            }
            *(h4*)&wsm[r][k4 * 4] = hv;
        }
    }
    __syncthreads();
#pragma unroll
    for (int ks = 0; ks < 3; ++ks) {
        h8 a = *(const h8*)&hs[16 * w + l15][ks * 32 + lg * 8];
#pragma unroll
        for (int ct = 0; ct < 3; ++ct) {
            h8 b = *(const h8*)&wsm[ct * 16 + l15][ks * 32 + lg * 8];
            acc[ct] = __builtin_amdgcn_mfma_f32_16x16x32_f16(a, b, acc[ct], 0, 0, 0);
        }
    }
#pragma unroll
    for (int r = 0; r < 4; ++r) {
        int grow = row0 + 16 * w + lg * 4 + r;
        if (grow < n) {
#pragma unroll
            for (int ct = 0; ct < 3; ++ct) {
                int colc = ct * 16 + l15;
                if (colc < FC)
                    g1h[(size_t)grow * FC + colc] = (_Float16)acc[ct][r];
            }
        }
    }
}

// ---------------- aggregation 40 + log_softmax fused: 5 threads/node h8, 50 nodes/block ----------------

__global__ __launch_bounds__(256) void k_agg40lsm(const _Float16* __restrict__ g1h,
                                                  const unsigned* __restrict__ off,
                                                  const unsigned* __restrict__ epk,
                                                  const float* __restrict__ dinv,
                                                  const float* __restrict__ b,
                                                  float* __restrict__ out, int n) {
    __shared__ float sm[50][41];
    int tid = threadIdx.x;
    int ln = tid / 5;
    int f8 = tid - ln * 5;
    int node = blockIdx.x * 50 + ln;
    bool active = (tid < 250) && (node < n);
    float acc[8];
#pragma unroll
    for (int j = 0; j < 8; ++j) acc[j] = 0.f;
    if (active) {
        float s = dinv[node];
        const h8* gp = (const h8*)g1h;  // row = 5 h8 chunks
        h8 self = gp[(size_t)node * 5 + f8];
#pragma unroll
        for (int j = 0; j < 8; ++j) acc[j] = s * (float)self[j];
        unsigned st = off[node], en = off[node + 1];
        unsigned e = st;
        for (; e + 4 <= en; e += 4) {
            unsigned k0 = epk[e + 0], k1 = epk[e + 1], k2 = epk[e + 2], k3 = epk[e + 3];
            h8 ga = gp[(size_t)(k0 & 0xffffu) * 5 + f8];
            h8 gb = gp[(size_t)(k1 & 0xffffu) * 5 + f8];
            h8 gc = gp[(size_t)(k2 & 0xffffu) * 5 + f8];
            h8 gd = gp[(size_t)(k3 & 0xffffu) * 5 + f8];
            float w0 = unpack_w(k0), w1 = unpack_w(k1), w2 = unpack_w(k2), w3 = unpack_w(k3);
#pragma unroll
            for (int j = 0; j < 8; ++j) acc[j] = fmaf(w0, (float)ga[j], acc[j]);
#pragma unroll
            for (int j = 0; j < 8; ++j) acc[j] = fmaf(w1, (float)gb[j], acc[j]);
#pragma unroll
            for (int j = 0; j < 8; ++j) acc[j] = fmaf(w2, (float)gc[j], acc[j]);
#pragma unroll
            for (int j = 0; j < 8; ++j) acc[j] = fmaf(w3, (float)gd[j], acc[j]);
        }
        for (; e < en; ++e) {
            unsigned k = epk[e];
            h8 g = gp[(size_t)(k & 0xffffu) * 5 + f8];
            float wv = unpack_w(k);
#pragma unroll
            for (int j = 0; j < 8; ++j) acc[j] = fmaf(wv, (float)g[j], acc[j]);
        }
        float4 bv0 = ((const float4*)b)[f8 * 2];
        float4 bv1 = ((const float4*)b)[f8 * 2 + 1];
        const float bb[8] = {bv0.x, bv0.y, bv0.z, bv0.w, bv1.x, bv1.y, bv1.z, bv1.w};
#pragma unroll
        for (int j = 0; j < 8; ++j) {
            acc[j] = fmaf(s, acc[j], bb[j]);
            sm[ln][f8 * 8 + j] = acc[j];
        }
    }
    __syncthreads();
    if (tid < 50) {
        int nd = blockIdx.x * 50 + tid;
        if (nd < n) {
            float m = -INFINITY;
#pragma unroll 8
            for (int j = 0; j < FC; ++j) m = fmaxf(m, sm[tid][j]);
            float sum = 0.f;
#pragma unroll 8
            for (int j = 0; j < FC; ++j) sum += expf(sm[tid][j] - m);
            sm[tid][40] = logf(sum) + m;
        }
    }
    __syncthreads();
    if (active) {
        float lse = sm[ln][40];
        float4 o0 = make_float4(acc[0] - lse, acc[1] - lse, acc[2] - lse, acc[3] - lse);
        float4 o1 = make_float4(acc[4] - lse, acc[5] - lse, acc[6] - lse, acc[7] - lse);
        *(float4*)&out[(size_t)node * FC + f8 * 8] = o0;
        *(float4*)&out[(size_t)node * FC + f8 * 8 + 4] = o1;
    }
}

// ---------------- launch ----------------

extern "C" void kernel_launch(void* const* d_in, const int* in_sizes, int n_in,
                              void* d_out, int out_size, void* d_ws, size_t ws_size,
                              hipStream_t stream) {
    const float* x  = (const float*)d_in[0];
    const int*   ei = (const int*)d_in[1];
    const float* ew = (const float*)d_in[2];
    const float* W1 = (const float*)d_in[3];
    const float* b1 = (const float*)d_in[4];
    const float* W2 = (const float*)d_in[5];
    const float* b2 = (const float*)d_in[6];
    float* out = (float*)d_out;

    const int N = NN;
    const int E = in_sizes[1] / 2;
    const int* row = ei;
    const int* col = ei + E;

    float* ws = (float*)d_ws;
    // workspace layout (4-byte words)
    // dinv   [0, 50176)
    // off    [50176, 100480)  N+1
    // bcnt2d [100480, 116864) 64x256
    // bstart [116864, 117120)
    // gcur   [117120, 117376)
    // overlays of region R = [150976, 4950976):
    //   copies [150976, 950976) (128 x 6250)           : k_fused1 -> k_reduce
    //   bkc [150976, 950976), bkpk [950976, 1750976)   : k_bucket -> k_place
    //   h   [150976, 2550976) (fp16 N*96)              : k_agg96 -> k_gemm2
    // epk [4950976, 5750976) u32: k_place -> k_agg40lsm
    // g0h [6550976, 8950976) (fp16 N*96 raw): k_fused1 -> k_agg96
    // g1h [8950976, 9950976) (fp16 N*40 raw): k_gemm2 -> k_agg40lsm
    float*    dinv   = (float*)(ws + 0);
    unsigned* off    = (unsigned*)(ws + 50176);
    unsigned* bcnt2d = (unsigned*)(ws + 100480);
    unsigned* bstart = (unsigned*)(ws + 116864);
    unsigned* gcur   = (unsigned*)(ws + 117120);
    unsigned* copies = (unsigned*)(ws + 150976);
    unsigned* bkc    = (unsigned*)(ws + 150976);
    unsigned* bkpk   = (unsigned*)(ws + 950976);
    _Float16* h      = (_Float16*)(ws + 150976);
    unsigned* epk    = (unsigned*)(ws + 4950976);
    _Float16* g0h    = (_Float16*)(ws + 6550976);
    _Float16* g1h    = (_Float16*)(ws + 8950976);

    const int B = 256;

    hipLaunchKernelGGL(k_fused1, dim3(974), dim3(B), 0, stream,
                       x, W1, g0h, ei, E, copies, bcnt2d, N);
    hipLaunchKernelGGL(k_reduce, dim3(98), dim3(B), 0, stream,
                       copies, bcnt2d, dinv, bstart, gcur, off, (unsigned)E);

    hipLaunchKernelGGL(k_bucket, dim3(320), dim3(B), 0, stream,
                       row, col, ew, dinv, gcur, bkc, bkpk, E);
    hipLaunchKernelGGL(k_place, dim3(NBK), dim3(B), 0, stream, bkc, bkpk, bstart, off, epk, N);

    hipLaunchKernelGGL(k_agg96, dim3((N * 12 + B - 1) / B), dim3(B), 0, stream,
                       g0h, off, epk, dinv, b1, h, N);

    hipLaunchKernelGGL(k_gemm2, dim3((N + 63) / 64), dim3(B), 0, stream, h, W2, g1h, N);

    hipLaunchKernelGGL(k_agg40lsm, dim3((N + 49) / 50), dim3(B), 0, stream,
                       g1h, off, epk, dinv, b2, out, N);
}

// Round 16
// 123.992 us; speedup vs baseline: 1.0999x; 1.0999x over previous
//
#include <hip/hip_runtime.h>
#include <hip/hip_bf16.h>
#include <hip/hip_fp16.h>
#include <math.h>

#define NN 50000
#define EE 800000
#define FIN 256
#define FH 96
#define FC 40
#define NBK 196   // ceil(50000/256) buckets of 256 nodes

typedef _Float16 h4 __attribute__((ext_vector_type(4)));
typedef _Float16 h8 __attribute__((ext_vector_type(8)));
typedef float f32x4 __attribute__((ext_vector_type(4)));

// pack: low16 = row (N<65536), high16 = fp16 bits of w (= dinv[row]*ew)
__device__ __forceinline__ unsigned pack_edge(int row, float w) {
    _Float16 he = (_Float16)w;
    unsigned short us;
    __builtin_memcpy(&us, &he, 2);
    return (unsigned)row | ((unsigned)us << 16);
}
__device__ __forceinline__ float unpack_w(unsigned pk) {
    unsigned short us = (unsigned short)(pk >> 16);
    _Float16 hv;
    __builtin_memcpy(&hv, &us, 2);
    return (float)hv;
}

// ---------------- fused launch 1 (25 KB LDS for all branches) ----------------
// blocks [0,782): GEMM1 (MFMA fp16, raw x@W1^T), register-prefetch pipelined
// blocks [782,910): row-degree histogram, 2 halves x 64 slices, 8-BIT bins (4 nodes/word)
//   (per-(slice,node) count <= node degree << 255 -> no overflow)
// blocks [910,974): col bucket-count -> private bcnt2d rows

#define G1B 782

__global__ __launch_bounds__(256) void k_fused1(const float* __restrict__ x,
                                                const float* __restrict__ W,
                                                _Float16* __restrict__ g0h,
                                                const int* __restrict__ ei, int E,
                                                unsigned* __restrict__ copies,
                                                unsigned* __restrict__ bcnt2d, int n) {
    __shared__ unsigned lds[6250];   // 25000 B; gemm branch uses 23040 B of it
    int bid = blockIdx.x;
    int tid = threadIdx.x;

    if (bid < G1B) {
        // ---- GEMM1, prefetch-pipelined ----
        _Float16* xsp = (_Float16*)lds;          // [64][72]
        _Float16* wsp = xsp + 64 * 72;           // [96][72]
        int row0 = bid * 64;
        int l = tid & 63, w = tid >> 6;
        int l15 = l & 15, lg = l >> 4;

        f32x4 acc[6];
#pragma unroll
        for (int c = 0; c < 6; ++c) acc[c] = (f32x4)0.f;

        float4 px[4], pw[6];
        // load chunk 0
        {
#pragma unroll
            for (int i = 0; i < 4; ++i) {
                int it = tid + 256 * i;
                int r = it >> 4, k4 = it & 15;
                int gr = row0 + r;
                px[i] = make_float4(0.f, 0.f, 0.f, 0.f);
                if (gr < n) px[i] = *(const float4*)&x[gr * FIN + k4 * 4];
            }
#pragma unroll
            for (int i = 0; i < 6; ++i) {
                int it = tid + 256 * i;
                int r = it >> 4, k4 = it & 15;
                pw[i] = *(const float4*)&W[r * FIN + k4 * 4];
            }
        }
        for (int kc = 0; kc < 4; ++kc) {
            // store current chunk to LDS
#pragma unroll
            for (int i = 0; i < 4; ++i) {
                int it = tid + 256 * i;
                int r = it >> 4, k4 = it & 15;
                h4 hv = {(_Float16)px[i].x, (_Float16)px[i].y, (_Float16)px[i].z, (_Float16)px[i].w};
                *(h4*)&xsp[r * 72 + k4 * 4] = hv;
            }
#pragma unroll
            for (int i = 0; i < 6; ++i) {
                int it = tid + 256 * i;
                int r = it >> 4, k4 = it & 15;
                h4 hv = {(_Float16)pw[i].x, (_Float16)pw[i].y, (_Float16)pw[i].z, (_Float16)pw[i].w};
                *(h4*)&wsp[r * 72 + k4 * 4] = hv;
            }
            // issue next chunk's loads (latency hides under MFMA + syncs)
            if (kc < 3) {
                int kbase = (kc + 1) * 64;
#pragma unroll
                for (int i = 0; i < 4; ++i) {
                    int it = tid + 256 * i;
                    int r = it >> 4, k4 = it & 15;
                    int gr = row0 + r;
                    px[i] = make_float4(0.f, 0.f, 0.f, 0.f);
                    if (gr < n) px[i] = *(const float4*)&x[gr * FIN + kbase + k4 * 4];
                }
#pragma unroll
                for (int i = 0; i < 6; ++i) {
                    int it = tid + 256 * i;
                    int r = it >> 4, k4 = it & 15;
                    pw[i] = *(const float4*)&W[r * FIN + kbase + k4 * 4];
                }
            }
            __syncthreads();
#pragma unroll
            for (int ks = 0; ks < 2; ++ks) {
                h8 a = *(const h8*)&xsp[(16 * w + l15) * 72 + ks * 32 + lg * 8];
#pragma unroll
                for (int ct = 0; ct < 6; ++ct) {
                    h8 b = *(const h8*)&wsp[(ct * 16 + l15) * 72 + ks * 32 + lg * 8];
                    acc[ct] = __builtin_amdgcn_mfma_f32_16x16x32_f16(a, b, acc[ct], 0, 0, 0);
                }
            }
            __syncthreads();
        }
#pragma unroll
        for (int r = 0; r < 4; ++r) {
            int grow = row0 + 16 * w + lg * 4 + r;
            if (grow < n) {
#pragma unroll
                for (int ct = 0; ct < 6; ++ct)
                    g0h[(size_t)grow * FH + ct * 16 + l15] = (_Float16)acc[ct][r];
            }
        }
    } else if (bid < 910) {
        // ---- row-degree histogram: half h, slice of E/64, 8-bit bins ----
        int b2 = bid - G1B;           // 0..127
        int half = b2 >> 6;           // 0..1
        int slice = b2 & 63;          // 0..63
        int ES = (E + 63) >> 6;       // 12500
        const int* ptr = ei;          // row
        for (int i = tid; i < 6250; i += 256) lds[i] = 0u;
        __syncthreads();
        int lo = slice * ES, hi = min(lo + ES, E);
        int nlo = half * 25000;
        for (int i = lo + tid; i < hi; i += 256) {
            int rel = ptr[i] - nlo;
            if ((unsigned)rel < 25000u)
                atomicAdd(&lds[rel >> 2], 1u << ((rel & 3) << 3));
        }
        __syncthreads();
        unsigned* dst = copies + (size_t)b2 * 6250;
        for (int i = tid; i < 6250; i += 256) dst[i] = lds[i];
    } else {
        // ---- col bucket-count (private row per chunk) ----
        int chunk = bid - 910;
        int ES = (E + 63) >> 6;
        const int* col = ei + E;
        for (int i = tid; i < NBK; i += 256) lds[i] = 0u;
        __syncthreads();
        int lo = chunk * ES, hi = min(lo + ES, E);
        for (int i = lo + tid; i < hi; i += 256) atomicAdd(&lds[col[i] >> 8], 1u);
        __syncthreads();
        for (int i = tid; i < NBK; i += 256) bcnt2d[chunk * 256 + i] = lds[i];
    }
}

// ---------------- reduce row-copies (8-bit unpack) -> dinv; block 0 scans bcnt2d ----------------

__global__ __launch_bounds__(256) void k_reduce(const unsigned* __restrict__ copies,
                                                const unsigned* __restrict__ bcnt2d,
                                                float* __restrict__ dinv,
                                                unsigned* __restrict__ bstart,
                                                unsigned* __restrict__ gcur,
                                                unsigned* __restrict__ off, unsigned E) {
    int t = blockIdx.x * blockDim.x + threadIdx.x;  // 0..12499 (each = 4 nodes)
    if (t < 12500) {
        int half = t / 6250, w = t - half * 6250;
        unsigned s0 = 0, s1 = 0, s2 = 0, s3 = 0;
        const unsigned* br = copies + (size_t)(half * 64) * 6250 + w;
#pragma unroll 8
        for (int s = 0; s < 64; ++s) {
            unsigned v = br[s * 6250];
            s0 += v & 0xffu;
            s1 += (v >> 8) & 0xffu;
            s2 += (v >> 16) & 0xffu;
            s3 += (v >> 24);
        }
        int n0 = half * 25000 + 4 * w;
        dinv[n0 + 0] = rsqrtf((float)(s0 + 1u));
        dinv[n0 + 1] = rsqrtf((float)(s1 + 1u));
        dinv[n0 + 2] = rsqrtf((float)(s2 + 1u));
        dinv[n0 + 3] = rsqrtf((float)(s3 + 1u));
    }
    if (blockIdx.x == 0) {
        __shared__ unsigned sb[256];
        int tt = threadIdx.x;
        unsigned v = 0;
        if (tt < NBK) {
#pragma unroll 8
            for (int c = 0; c < 64; ++c) v += bcnt2d[c * 256 + tt];
        }
        sb[tt] = v;
        __syncthreads();
        for (int o = 1; o < 256; o <<= 1) {
            unsigned tv = (tt >= o) ? sb[tt - o] : 0u;
            __syncthreads();
            sb[tt] += tv;
            __syncthreads();
        }
        if (tt < NBK) {
            unsigned ex = sb[tt] - v;     // exclusive
            bstart[tt] = ex;
            gcur[tt] = ex;
            bstart[tt + 1] = sb[tt];
        }
        if (tt == 0) off[NN] = E;
    }
}

// ---------------- P1: coarse bucket by col>>8; payload packs dinv[row]*ew ----------------

__global__ __launch_bounds__(256) void k_bucket(const int* __restrict__ row,
                                                const int* __restrict__ col,
                                                const float* __restrict__ ew,
                                                const float* __restrict__ dinv,
                                                unsigned* __restrict__ gcur,
                                                unsigned* __restrict__ bkc,
                                                unsigned* __restrict__ bkpk, int E) {
    __shared__ unsigned cnt[NBK];
    __shared__ unsigned cur[NBK];
    int tid = threadIdx.x;
    int CH = (E + gridDim.x - 1) / gridDim.x;
    int lo = blockIdx.x * CH, hi = min(lo + CH, E);
    for (int i = tid; i < NBK; i += 256) cnt[i] = 0u;
    __syncthreads();
    for (int i = lo + tid; i < hi; i += 256) atomicAdd(&cnt[col[i] >> 8], 1u);
    __syncthreads();
    for (int i = tid; i < NBK; i += 256) cur[i] = atomicAdd(&gcur[i], cnt[i]);
    __syncthreads();
    for (int i = lo + tid; i < hi; i += 256) {
        int c = col[i];
        int r = row[i];
        unsigned pos = atomicAdd(&cur[c >> 8], 1u);
        bkc[pos] = (unsigned)c;
        bkpk[pos] = pack_edge(r, dinv[r] * ew[i]);
    }
}

// ---------------- P2: per-bucket count + scan -> off[], then exact place ----------------

__global__ __launch_bounds__(256) void k_place(const unsigned* __restrict__ bkc,
                                               const unsigned* __restrict__ bkpk,
                                               const unsigned* __restrict__ bstart,
                                               unsigned* __restrict__ off,
                                               unsigned* __restrict__ epk, int n) {
    __shared__ unsigned cnt[256];
    __shared__ unsigned cur[256];
    int b = blockIdx.x;
    int tid = threadIdx.x;
    int node0 = b * 256;
    unsigned st = bstart[b], en = bstart[b + 1];
    cnt[tid] = 0u;
    __syncthreads();
    for (unsigned i = st + tid; i < en; i += 256) atomicAdd(&cnt[bkc[i] & 255], 1u);
    __syncthreads();
    unsigned v = cnt[tid];
    cur[tid] = v;
    __syncthreads();
    for (int o = 1; o < 256; o <<= 1) {
        unsigned tv = (tid >= o) ? cur[tid - o] : 0u;
        __syncthreads();
        cur[tid] += tv;
        __syncthreads();
    }
    unsigned base = st + cur[tid] - v;
    int node = node0 + tid;
    if (node < n) off[node] = base;
    cur[tid] = base;
    __syncthreads();
    for (unsigned i = st + tid; i < en; i += 256) {
        unsigned c = bkc[i];
        unsigned pos = atomicAdd(&cur[c & 255], 1u);
        epk[pos] = bkpk[i];
    }
}

// ---------------- aggregation 96: 12 threads/node, h8 gathers, unroll-8/4 ----------------

__global__ __launch_bounds__(256) void k_agg96(const _Float16* __restrict__ g0h,
                                               const unsigned* __restrict__ off,
                                               const unsigned* __restrict__ epk,
                                               const float* __restrict__ dinv,
                                               const float* __restrict__ b,
                                               _Float16* __restrict__ outh, int n) {
    int tid = blockIdx.x * 256 + threadIdx.x;
    int node = tid / 12;
    int f8 = tid - node * 12;
    if (node >= n) return;
    float s = dinv[node];
    const h8* gp = (const h8*)g0h;  // row = 12 h8 chunks
    h8 self = gp[(size_t)node * 12 + f8];
    float acc[8];
#pragma unroll
    for (int j = 0; j < 8; ++j) acc[j] = s * (float)self[j];
    unsigned st = off[node], en = off[node + 1];
    unsigned e = st;
    for (; e + 8 <= en; e += 8) {
        unsigned k0 = epk[e + 0], k1 = epk[e + 1], k2 = epk[e + 2], k3 = epk[e + 3];
        unsigned k4 = epk[e + 4], k5 = epk[e + 5], k6 = epk[e + 6], k7 = epk[e + 7];
        h8 ga = gp[(size_t)(k0 & 0xffffu) * 12 + f8];
        h8 gb = gp[(size_t)(k1 & 0xffffu) * 12 + f8];
        h8 gc = gp[(size_t)(k2 & 0xffffu) * 12 + f8];
        h8 gd = gp[(size_t)(k3 & 0xffffu) * 12 + f8];
        h8 ge = gp[(size_t)(k4 & 0xffffu) * 12 + f8];
        h8 gf = gp[(size_t)(k5 & 0xffffu) * 12 + f8];
        h8 gg = gp[(size_t)(k6 & 0xffffu) * 12 + f8];
        h8 gh = gp[(size_t)(k7 & 0xffffu) * 12 + f8];
        float w0 = unpack_w(k0), w1 = unpack_w(k1), w2 = unpack_w(k2), w3 = unpack_w(k3);
        float w4 = unpack_w(k4), w5 = unpack_w(k5), w6 = unpack_w(k6), w7 = unpack_w(k7);
#pragma unroll
        for (int j = 0; j < 8; ++j) acc[j] = fmaf(w0, (float)ga[j], acc[j]);
#pragma unroll
        for (int j = 0; j < 8; ++j) acc[j] = fmaf(w1, (float)gb[j], acc[j]);
#pragma unroll
        for (int j = 0; j < 8; ++j) acc[j] = fmaf(w2, (float)gc[j], acc[j]);
#pragma unroll
        for (int j = 0; j < 8; ++j) acc[j] = fmaf(w3, (float)gd[j], acc[j]);
#pragma unroll
        for (int j = 0; j < 8; ++j) acc[j] = fmaf(w4, (float)ge[j], acc[j]);
#pragma unroll
        for (int j = 0; j < 8; ++j) acc[j] = fmaf(w5, (float)gf[j], acc[j]);
#pragma unroll
        for (int j = 0; j < 8; ++j) acc[j] = fmaf(w6, (float)gg[j], acc[j]);
#pragma unroll
        for (int j = 0; j < 8; ++j) acc[j] = fmaf(w7, (float)gh[j], acc[j]);
    }
    for (; e + 4 <= en; e += 4) {
        unsigned k0 = epk[e + 0], k1 = epk[e + 1], k2 = epk[e + 2], k3 = epk[e + 3];
        h8 ga = gp[(size_t)(k0 & 0xffffu) * 12 + f8];
        h8 gb = gp[(size_t)(k1 & 0xffffu) * 12 + f8];
        h8 gc = gp[(size_t)(k2 & 0xffffu) * 12 + f8];
        h8 gd = gp[(size_t)(k3 & 0xffffu) * 12 + f8];
        float w0 = unpack_w(k0), w1 = unpack_w(k1), w2 = unpack_w(k2), w3 = unpack_w(k3);
#pragma unroll
        for (int j = 0; j < 8; ++j) acc[j] = fmaf(w0, (float)ga[j], acc[j]);
#pragma unroll
        for (int j = 0; j < 8; ++j) acc[j] = fmaf(w1, (float)gb[j], acc[j]);
#pragma unroll
        for (int j = 0; j < 8; ++j) acc[j] = fmaf(w2, (float)gc[j], acc[j]);
#pragma unroll
        for (int j = 0; j < 8; ++j) acc[j] = fmaf(w3, (float)gd[j], acc[j]);
    }
    for (; e < en; ++e) {
        unsigned k = epk[e];
        h8 g = gp[(size_t)(k & 0xffffu) * 12 + f8];
        float wv = unpack_w(k);
#pragma unroll
        for (int j = 0; j < 8; ++j) acc[j] = fmaf(wv, (float)g[j], acc[j]);
    }
    float4 bv0 = ((const float4*)b)[f8 * 2];
    float4 bv1 = ((const float4*)b)[f8 * 2 + 1];
    const float bb[8] = {bv0.x, bv0.y, bv0.z, bv0.w, bv1.x, bv1.y, bv1.z, bv1.w};
    h8 o;
#pragma unroll
    for (int j = 0; j < 8; ++j) o[j] = (_Float16)fmaxf(fmaf(s, acc[j], bb[j]), 0.f);
    *(h8*)&outh[(size_t)node * FH + f8 * 8] = o;
}

// ---------------- GEMM2 (MFMA fp16): g1h = fp16( h @ W2^T ) raw ----------------

__global__ __launch_bounds__(256) void k_gemm2(const _Float16* __restrict__ h,
                                               const float* __restrict__ W2,
                                               _Float16* __restrict__ g1h, int n) {
    __shared__ _Float16 hs[64][104];
    __shared__ _Float16 wsm[48][104];
    int tid = threadIdx.x;
    int row0 = blockIdx.x * 64;
    int l = tid & 63, w = tid >> 6;
    int l15 = l & 15, lg = l >> 4;

    f32x4 acc[3];
#pragma unroll
    for (int c = 0; c < 3; ++c) acc[c] = (f32x4)0.f;

#pragma unroll
    for (int i = 0; i < 6; ++i) {
        int it = tid + 256 * i;
        int r = it / 24, k4 = it - r * 24;
        int gr = row0 + r;
        h4 hv = {(_Float16)0.f, (_Float16)0.f, (_Float16)0.f, (_Float16)0.f};
        if (gr < n) hv = *(const h4*)&h[(size_t)gr * FH + k4 * 4];
        *(h4*)&hs[r][k4 * 4] = hv;
    }
#pragma unroll
    for (int i = 0; i < 5; ++i) {
        int it = tid + 256 * i;
        if (it < 1152) {
            int r = it / 24, k4 = it - r * 24;
            h4 hv = {(_Float16)0.f, (_Float16)0.f, (_Float16)0.f, (_Float16)0.f};
            if (r < FC) {
                float4 v = *(const float4*)&W2[r * FH + k4 * 4];
                hv[0] = (_Float16)v.x; hv[1] = (_Float16)v.y;
                hv[2] = (_Float16)v.z; hv[3] = (_Float16)v.w;
            }
            *(h4*)&wsm[r][k4 * 4] = hv;
        }
    }
    __syncthreads();
#pragma unroll
    for (int ks = 0; ks < 3; ++ks) {
        h8 a = *(const h8*)&hs[16 * w + l15][ks * 32 + lg * 8];
#pragma unroll
        for (int ct = 0; ct < 3; ++ct) {
            h8 b = *(const h8*)&wsm[ct * 16 + l15][ks * 32 + lg * 8];
            acc[ct] = __builtin_amdgcn_mfma_f32_16x16x32_f16(a, b, acc[ct], 0, 0, 0);
        }
    }
#pragma unroll
    for (int r = 0; r < 4; ++r) {
        int grow = row0 + 16 * w + lg * 4 + r;
        if (grow < n) {
#pragma unroll
            for (int ct = 0; ct < 3; ++ct) {
                int colc = ct * 16 + l15;
                if (colc < FC)
                    g1h[(size_t)grow * FC + colc] = (_Float16)acc[ct][r];
            }
        }
    }
}

// ---------------- aggregation 40 + log_softmax fused: 5 threads/node h8, 50 nodes/block ----------------

__global__ __launch_bounds__(256) void k_agg40lsm(const _Float16* __restrict__ g1h,
                                                  const unsigned* __restrict__ off,
                                                  const unsigned* __restrict__ epk,
                                                  const float* __restrict__ dinv,
                                                  const float* __restrict__ b,
                                                  float* __restrict__ out, int n) {
    __shared__ float sm[50][41];
    int tid = threadIdx.x;
    int ln = tid / 5;
    int f8 = tid - ln * 5;
    int node = blockIdx.x * 50 + ln;
    bool active = (tid < 250) && (node < n);
    float acc[8];
#pragma unroll
    for (int j = 0; j < 8; ++j) acc[j] = 0.f;
    if (active) {
        float s = dinv[node];
        const h8* gp = (const h8*)g1h;  // row = 5 h8 chunks
        h8 self = gp[(size_t)node * 5 + f8];
#pragma unroll
        for (int j = 0; j < 8; ++j) acc[j] = s * (float)self[j];
        unsigned st = off[node], en = off[node + 1];
        unsigned e = st;
        for (; e + 4 <= en; e += 4) {
            unsigned k0 = epk[e + 0], k1 = epk[e + 1], k2 = epk[e + 2], k3 = epk[e + 3];
            h8 ga = gp[(size_t)(k0 & 0xffffu) * 5 + f8];
            h8 gb = gp[(size_t)(k1 & 0xffffu) * 5 + f8];
            h8 gc = gp[(size_t)(k2 & 0xffffu) * 5 + f8];
            h8 gd = gp[(size_t)(k3 & 0xffffu) * 5 + f8];
            float w0 = unpack_w(k0), w1 = unpack_w(k1), w2 = unpack_w(k2), w3 = unpack_w(k3);
#pragma unroll
            for (int j = 0; j < 8; ++j) acc[j] = fmaf(w0, (float)ga[j], acc[j]);
#pragma unroll
            for (int j = 0; j < 8; ++j) acc[j] = fmaf(w1, (float)gb[j], acc[j]);
#pragma unroll
            for (int j = 0; j < 8; ++j) acc[j] = fmaf(w2, (float)gc[j], acc[j]);
#pragma unroll
            for (int j = 0; j < 8; ++j) acc[j] = fmaf(w3, (float)gd[j], acc[j]);
        }
        for (; e < en; ++e) {
            unsigned k = epk[e];
            h8 g = gp[(size_t)(k & 0xffffu) * 5 + f8];
            float wv = unpack_w(k);
#pragma unroll
            for (int j = 0; j < 8; ++j) acc[j] = fmaf(wv, (float)g[j], acc[j]);
        }
        float4 bv0 = ((const float4*)b)[f8 * 2];
        float4 bv1 = ((const float4*)b)[f8 * 2 + 1];
        const float bb[8] = {bv0.x, bv0.y, bv0.z, bv0.w, bv1.x, bv1.y, bv1.z, bv1.w};
#pragma unroll
        for (int j = 0; j < 8; ++j) {
            acc[j] = fmaf(s, acc[j], bb[j]);
            sm[ln][f8 * 8 + j] = acc[j];
        }
    }
    __syncthreads();
    if (tid < 50) {
        int nd = blockIdx.x * 50 + tid;
        if (nd < n) {
            float m = -INFINITY;
#pragma unroll 8
            for (int j = 0; j < FC; ++j) m = fmaxf(m, sm[tid][j]);
            float sum = 0.f;
#pragma unroll 8
            for (int j = 0; j < FC; ++j) sum += expf(sm[tid][j] - m);
            sm[tid][40] = logf(sum) + m;
        }
    }
    __syncthreads();
    if (active) {
        float lse = sm[ln][40];
        float4 o0 = make_float4(acc[0] - lse, acc[1] - lse, acc[2] - lse, acc[3] - lse);
        float4 o1 = make_float4(acc[4] - lse, acc[5] - lse, acc[6] - lse, acc[7] - lse);
        *(float4*)&out[(size_t)node * FC + f8 * 8] = o0;
        *(float4*)&out[(size_t)node * FC + f8 * 8 + 4] = o1;
    }
}

// ---------------- launch ----------------

extern "C" void kernel_launch(void* const* d_in, const int* in_sizes, int n_in,
                              void* d_out, int out_size, void* d_ws, size_t ws_size,
                              hipStream_t stream) {
    const float* x  = (const float*)d_in[0];
    const int*   ei = (const int*)d_in[1];
    const float* ew = (const float*)d_in[2];
    const float* W1 = (const float*)d_in[3];
    const float* b1 = (const float*)d_in[4];
    const float* W2 = (const float*)d_in[5];
    const float* b2 = (const float*)d_in[6];
    float* out = (float*)d_out;

    const int N = NN;
    const int E = in_sizes[1] / 2;
    const int* row = ei;
    const int* col = ei + E;

    float* ws = (float*)d_ws;
    // workspace layout (4-byte words)
    // dinv   [0, 50176)
    // off    [50176, 100480)  N+1
    // bcnt2d [100480, 116864) 64x256
    // bstart [116864, 117120)
    // gcur   [117120, 117376)
    // overlays of region R = [150976, 4950976):
    //   copies [150976, 950976) (128 x 6250, 8-bit bins) : k_fused1 -> k_reduce
    //   bkc [150976, 950976), bkpk [950976, 1750976)     : k_bucket -> k_place
    //   h   [150976, 2550976) (fp16 N*96)                : k_agg96 -> k_gemm2
    // epk [4950976, 5750976) u32: k_place -> k_agg40lsm
    // g0h [6550976, 8950976) (fp16 N*96 raw): k_fused1 -> k_agg96
    // g1h [8950976, 9950976) (fp16 N*40 raw): k_gemm2 -> k_agg40lsm
    float*    dinv   = (float*)(ws + 0);
    unsigned* off    = (unsigned*)(ws + 50176);
    unsigned* bcnt2d = (unsigned*)(ws + 100480);
    unsigned* bstart = (unsigned*)(ws + 116864);
    unsigned* gcur   = (unsigned*)(ws + 117120);
    unsigned* copies = (unsigned*)(ws + 150976);
    unsigned* bkc    = (unsigned*)(ws + 150976);
    unsigned* bkpk   = (unsigned*)(ws + 950976);
    _Float16* h      = (_Float16*)(ws + 150976);
    unsigned* epk    = (unsigned*)(ws + 4950976);
    _Float16* g0h    = (_Float16*)(ws + 6550976);
    _Float16* g1h    = (_Float16*)(ws + 8950976);

    const int B = 256;

    hipLaunchKernelGGL(k_fused1, dim3(974), dim3(B), 0, stream,
                       x, W1, g0h, ei, E, copies, bcnt2d, N);
    hipLaunchKernelGGL(k_reduce, dim3(49), dim3(B), 0, stream,
                       copies, bcnt2d, dinv, bstart, gcur, off, (unsigned)E);

    hipLaunchKernelGGL(k_bucket, dim3(320), dim3(B), 0, stream,
                       row, col, ew, dinv, gcur, bkc, bkpk, E);
    hipLaunchKernelGGL(k_place, dim3(NBK), dim3(B), 0, stream, bkc, bkpk, bstart, off, epk, N);

    hipLaunchKernelGGL(k_agg96, dim3((N * 12 + B - 1) / B), dim3(B), 0, stream,
                       g0h, off, epk, dinv, b1, h, N);

    hipLaunchKernelGGL(k_gemm2, dim3((N + 63) / 64), dim3(B), 0, stream, h, W2, g1h, N);

    hipLaunchKernelGGL(k_agg40lsm, dim3((N + 49) / 50), dim3(B), 0, stream,
                       g1h, off, epk, dinv, b2, out, N);
}